// Round 8
// baseline (350.523 us; speedup 1.0000x reference)
//
#include <hip/hip_runtime.h>

typedef float f32x4 __attribute__((ext_vector_type(4)));
typedef short bf16x8 __attribute__((ext_vector_type(8)));
typedef unsigned int u32x4 __attribute__((ext_vector_type(4)));
typedef _Float16 f16x2 __attribute__((ext_vector_type(2)));
typedef _Float16 f16x4 __attribute__((ext_vector_type(4)));

#define B_TOT 8192
#define D_ 64
#define K_ 16
#define H_ 5
#define IN_ 256

__device__ __forceinline__ unsigned short f2bf(float f){
  unsigned int u = __float_as_uint(f);
  u += 0x7fffu + ((u >> 16) & 1u);   // round-to-nearest-even
  return (unsigned short)(u >> 16);
}

__device__ __forceinline__ unsigned int cvtpk(float lo, float hi){
  unsigned int r;
  asm("v_cvt_pk_bf16_f32 %0, %1, %2" : "=v"(r) : "v"(lo), "v"(hi));
  return r;
}

// ---------------- Wpack2: pre-fragmented B for GEMM1 (layout verified r4/r5) ----------------
// elem[((j*8+kk)*192 + r)*4 + ks][e] = W[r][kk*32+ks*8+e]  (bf16)
// rows r: 0..79 W1(k*5+h), 80..95 Wx, 96..175 sW1, 176..191 sWx
__global__ void pack_weights2_kernel(const float* __restrict__ W1,
                                     const float* __restrict__ Wx,
                                     const float* __restrict__ sW1,
                                     const float* __restrict__ sWx,
                                     unsigned short* __restrict__ Wpack2){
  int j = blockIdx.x, r = blockIdx.y, c = threadIdx.x;
  const float* src;
  if (r < 80)      { int k = r/5, h = r%5;             src = W1  + (((k*D_ + j)*H_ + h)*IN_); }
  else if (r < 96) { int k = r-80;                     src = Wx  + ((k*D_ + j)*IN_); }
  else if (r < 176){ int rr = r-96; int k=rr/5,h=rr%5; src = sW1 + (((k*D_ + j)*H_ + h)*IN_); }
  else             { int k = r-176;                    src = sWx + ((k*D_ + j)*IN_); }
  int kk = c >> 5, ks = (c >> 3) & 3, e = c & 7;
  Wpack2[((((size_t)j*8 + kk)*192 + r)*4 + ks)*8 + e] = f2bf(src[c]);
}

// ---------------- b1pack[j][col 0..191] (f32; 0 on xdot cols) ----------------
__global__ void pack_b1_kernel(const float* __restrict__ b1, const float* __restrict__ sb1,
                               float* __restrict__ b1pack){
  int j = blockIdx.x, r = threadIdx.x;  // 192
  float v = 0.f;
  if (r < 80) v = b1[j*80 + r];
  else if (r >= 96 && r < 176) v = sb1[j*80 + (r-96)];
  b1pack[j*192 + r] = v;
}

// ---------------- B2packF: MFMA2 A-operand fragments (layout verified r5) ----------------
__global__ void pack_b2f_kernel(const float* __restrict__ Wh, const float* __restrict__ sWh,
                                unsigned short* __restrict__ B2packF){
  int j = blockIdx.x, kk = blockIdx.y, t = threadIdx.x;  // 256 thr, 1024 elems
  #pragma unroll
  for (int q = 0; q < 4; ++q){
    int f = t*4 + q;                 // r*32 + lg*8 + e
    int e = f & 7, lg = (f >> 3) & 3, r = f >> 5;
    int c = kk*32 + lg*8 + e;        // 0..95
    int k = r & 15;
    int h = c - 5*k;
    float v = 0.f;
    if (h >= 0 && h < 5) v = (r < 16 ? Wh : sWh)[((size_t)k*D_ + j)*H_ + h];
    B2packF[((size_t)j*3 + kk)*1024 + f] = f2bf(v);
  }
}

// ---------------- masked-softmax weights, packed as f16 MFMA A-fragment ----------------
// wf16[j][ (lg*16 + i)*4 + e ] = w[j][i][k=lg*4+e]
__global__ void compute_w_kernel(const float* __restrict__ targets, _Float16* __restrict__ wf16){
  int j = blockIdx.x;
  int i = threadIdx.x;
  if (i >= K_) return;
  float base[K_];
  base[0] = (i == 0) ? 1.f : 0.f;
  for (int c = 1; c <= i; ++c)
    base[c] = targets[(j*K_ + i)*(K_-1) + (c-1)] + ((c == i) ? 1.f : 0.f);
  float mx = base[0];
  for (int c = 1; c <= i; ++c) mx = fmaxf(mx, base[c]);
  float e[K_]; float s = 0.f;
  for (int c = 0; c <= i; ++c){ e[c] = expf(base[c] - mx); s += e[c]; }
  float inv = 1.f / s;
  for (int c = 0; c < K_; ++c){
    float w = (c <= i) ? e[c]*inv : 0.f;
    wf16[j*256 + ((c >> 2)*16 + i)*4 + (c & 3)] = (_Float16)w;
  }
}

// ---------------- main fused kernel: barrier-free, wave-private ----------------
// 2048 blocks x 256 thr (4 waves). Wave wv owns rows b0+wv*16..+15, all 192 cols, 4 j's.
// Per-wave LDS slice (8960 B): G[16][208]bf16 6656 | Gx[16][17]f32 1088 | Gsx[16][17]f32 1088
__global__ __launch_bounds__(256, 3)
void main_kernel(const float* __restrict__ x_values,
                 const float* __restrict__ x_inputs,
                 const unsigned short* __restrict__ Wpack2,
                 const _Float16* __restrict__ wf16,
                 const float* __restrict__ b1pack,
                 const unsigned short* __restrict__ B2packF,
                 const float* __restrict__ b2, const float* __restrict__ sb2,
                 float* __restrict__ partial){
  __shared__ __align__(16) char sm[35840];

  const int t    = threadIdx.x;
  const int lane = t & 63, wv = t >> 6;
  const int l15  = lane & 15, lg = lane >> 4;

  // XCD-aware swizzle: xcd = bx&7 gets jg in {xcd*2, xcd*2+1} (bijective, 2048 = 8*256)
  const int bx  = blockIdx.x;
  const int xcd = bx & 7, q8 = bx >> 3;       // q8 0..255
  const int bt  = q8 & 127, jg = xcd*2 + (q8 >> 7);
  const int b0  = bt * 64;

  char* Gw = sm + wv*8960;
  unsigned short* G = (unsigned short*)Gw;     // [16][208]
  float* Gx  = (float*)(Gw + 6656);            // [16][17]
  float* Gsx = (float*)(Gw + 7744);            // [16][17]

  const int myrow = b0 + wv*16 + l15;          // this lane's global b-row

  f32x4 acc3 = {0.f,0.f,0.f,0.f};

  for (int jj = 0; jj < 4; ++jj){
    const int j = jg*4 + jj;

    // E2 weight fragment (f16 A-frag) — tiny, L2-hot
    const f16x4 wfrag = *(const f16x4*)(wf16 + j*256 + lane*4);

    f32x4 acc1[12];
    #pragma unroll
    for (int n = 0; n < 12; ++n) acc1[n] = (f32x4){0.f,0.f,0.f,0.f};

    const float* aprow = x_inputs + ((size_t)myrow*D_ + j)*IN_;

    // ---- GEMM1: K=256 in 2 chunks; A direct-from-global, B frags from Wpack2 ----
    #pragma unroll
    for (int kc = 0; kc < 2; ++kc){
      // load the wave's A-rows for this K-chunk (8 x f32x4 = this lane's 32 f32)
      f32x4 av[8];
      #pragma unroll
      for (int kkl = 0; kkl < 4; ++kkl){
        av[kkl*2]   = *(const f32x4*)(aprow + kc*128 + kkl*32 + lg*8);
        av[kkl*2+1] = *(const f32x4*)(aprow + kc*128 + kkl*32 + lg*8 + 4);
      }
      #pragma unroll
      for (int kkl = 0; kkl < 4; ++kkl){
        u32x4 at;
        at[0] = cvtpk(av[kkl*2][0],   av[kkl*2][1]);
        at[1] = cvtpk(av[kkl*2][2],   av[kkl*2][3]);
        at[2] = cvtpk(av[kkl*2+1][0], av[kkl*2+1][1]);
        at[3] = cvtpk(av[kkl*2+1][2], av[kkl*2+1][3]);
        const bf16x8 af = __builtin_bit_cast(bf16x8, at);
        const unsigned short* wp = Wpack2 + (size_t)(j*8 + kc*4 + kkl)*6144 + l15*32 + lg*8;
        #pragma unroll
        for (int n = 0; n < 12; ++n){
          bf16x8 bfr = *(const bf16x8*)(wp + n*512);
          acc1[n] = __builtin_amdgcn_mfma_f32_16x16x32_bf16(af, bfr, acc1[n], 0, 0, 0);
        }
      }
    }

    // ---- G write: lrelu+b1 on hidden cols; xdot cols -> Gx/Gsx, zeros into G ----
    #pragma unroll
    for (int n = 0; n < 12; ++n){
      if (n == 5){
        #pragma unroll
        for (int e = 0; e < 4; ++e){
          Gx[(lg*4+e)*17 + l15] = acc1[5][e];
          G[(lg*4+e)*208 + 80 + l15] = 0;
        }
      } else if (n == 11){
        #pragma unroll
        for (int e = 0; e < 4; ++e){
          Gsx[(lg*4+e)*17 + l15] = acc1[11][e];
          G[(lg*4+e)*208 + 176 + l15] = 0;
        }
      } else {
        const float b1v = b1pack[j*192 + n*16 + l15];
        #pragma unroll
        for (int e = 0; e < 4; ++e){
          float v = acc1[n][e] + b1v;
          v = fmaxf(v, 0.2f*v);
          G[(lg*4+e)*208 + n*16 + l15] = f2bf(v);
        }
      }
    }

    // ---- MFMA2: D[k][brow] = W2 * G^T + (xdot + bias); wave-private, no barrier ----
    {
      f32x4 accm = *(const f32x4*)(Gx  + l15*17 + lg*4) + *(const f32x4*)(b2  + j*16 + lg*4);
      f32x4 accs = *(const f32x4*)(Gsx + l15*17 + lg*4) + *(const f32x4*)(sb2 + j*16 + lg*4);
      #pragma unroll
      for (int kk = 0; kk < 3; ++kk){
        bf16x8 a0 = *(const bf16x8*)(B2packF + ((size_t)j*3 + kk)*1024 + l15*32 + lg*8);
        bf16x8 a1 = *(const bf16x8*)(B2packF + ((size_t)j*3 + kk)*1024 + (16+l15)*32 + lg*8);
        bf16x8 g0 = *(const bf16x8*)((char*)G + l15*416       + kk*64 + lg*16);
        bf16x8 g1 = *(const bf16x8*)((char*)G + l15*416 + 192 + kk*64 + lg*16);
        accm = __builtin_amdgcn_mfma_f32_16x16x32_bf16(a0, g0, accm, 0, 0, 0);
        accs = __builtin_amdgcn_mfma_f32_16x16x32_bf16(a1, g1, accs, 0, 0, 0);
      }

      // ---- E1: nll nodes; lane holds k = lg*4+e for row brow = l15 ----
      const float xv = x_values[(size_t)myrow*D_ + j];
      float nn4[4];
      #pragma unroll
      for (int e = 0; e < 4; ++e){
        float mean = accm[e];
        float shv  = accs[e];
        float sg   = __fdividef(10.f, 1.f + __expf(-shv));
        float var  = fmaxf(sg*sg, 1e-6f);
        float d    = xv - mean;
        nn4[e] = 0.5f*(__logf(var) + __fdividef(d*d, var));
      }

      // ---- E2 as MFMA: acc3 += w(f16) x nll(f16); exact fragment match ----
      f16x2 p0 = __builtin_bit_cast(f16x2, __builtin_amdgcn_cvt_pkrtz(nn4[0], nn4[1]));
      f16x2 p1 = __builtin_bit_cast(f16x2, __builtin_amdgcn_cvt_pkrtz(nn4[2], nn4[3]));
      f16x4 nf = {p0[0], p0[1], p1[0], p1[1]};
      acc3 = __builtin_amdgcn_mfma_f32_16x16x16f16(wfrag, nf, acc3, 0, 0, 0);
    }
  }

  // final store: partial[jg][b][i], lane covers i = lg*4..+3 for b = myrow
  *(f32x4*)(partial + ((size_t)jg*B_TOT + myrow)*K_ + lg*4) = acc3;
}

// ---------------- final reduce over 16 j-groups ----------------
__global__ void reduce_kernel(const float* __restrict__ partial, float* __restrict__ out){
  int idx = blockIdx.x*256 + threadIdx.x;   // 131072
  float s = 0.f;
  #pragma unroll
  for (int g = 0; g < 16; ++g) s += partial[(size_t)g*(B_TOT*K_) + idx];
  out[idx] = s;
}

extern "C" void kernel_launch(void* const* d_in, const int* in_sizes, int n_in,
                              void* d_out, int out_size, void* d_ws, size_t ws_size,
                              hipStream_t stream){
  const float* x_values = (const float*)d_in[0];
  const float* x_inputs = (const float*)d_in[1];
  const float* targets  = (const float*)d_in[2];
  const float* W1  = (const float*)d_in[3];
  const float* b1  = (const float*)d_in[4];
  const float* Wh  = (const float*)d_in[5];
  const float* Wx  = (const float*)d_in[6];
  const float* b2  = (const float*)d_in[7];
  const float* sW1 = (const float*)d_in[8];
  const float* sb1 = (const float*)d_in[9];
  const float* sWh = (const float*)d_in[10];
  const float* sWx = (const float*)d_in[11];
  const float* sb2 = (const float*)d_in[12];
  (void)in_sizes; (void)n_in; (void)out_size; (void)ws_size;

  char* ws = (char*)d_ws;
  unsigned short* Wpack2  = (unsigned short*)ws;             // 6,291,456
  float* b1pack           = (float*)(ws + 6291456);          // 49,152
  unsigned short* B2packF = (unsigned short*)(ws + 6340608); // 393,216
  _Float16* wf16          = (_Float16*)(ws + 6733824);       // 32,768
  float* partial          = (float*)(ws + 6766592);          // 8,388,608
  float* out = (float*)d_out;

  pack_weights2_kernel<<<dim3(64, 192), 256, 0, stream>>>(W1, Wx, sW1, sWx, Wpack2);
  pack_b1_kernel<<<dim3(64), 192, 0, stream>>>(b1, sb1, b1pack);
  pack_b2f_kernel<<<dim3(64, 3), 256, 0, stream>>>(Wh, sWh, B2packF);
  compute_w_kernel<<<dim3(64), 64, 0, stream>>>(targets, wf16);
  main_kernel<<<dim3(2048), 256, 0, stream>>>(x_values, x_inputs, Wpack2, wf16,
                                              b1pack, B2packF, b2, sb2, partial);
  reduce_kernel<<<dim3(512), 256, 0, stream>>>(partial, out);
}

// Round 9
// 290.466 us; speedup vs baseline: 1.2068x; 1.2068x over previous
//
#include <hip/hip_runtime.h>

typedef float f32x4 __attribute__((ext_vector_type(4)));
typedef short bf16x8 __attribute__((ext_vector_type(8)));
typedef unsigned int u32x4 __attribute__((ext_vector_type(4)));
typedef _Float16 f16x2 __attribute__((ext_vector_type(2)));
typedef _Float16 f16x4 __attribute__((ext_vector_type(4)));

#define B_TOT 8192
#define D_ 64
#define K_ 16
#define H_ 5
#define IN_ 256

__device__ __forceinline__ unsigned short f2bf(float f){
  unsigned int u = __float_as_uint(f);
  u += 0x7fffu + ((u >> 16) & 1u);   // round-to-nearest-even
  return (unsigned short)(u >> 16);
}

__device__ __forceinline__ unsigned int cvtpk(float lo, float hi){
  unsigned int r;
  asm("v_cvt_pk_bf16_f32 %0, %1, %2" : "=v"(r) : "v"(lo), "v"(hi));
  return r;
}

// ---------------- Wpack2: pre-fragmented B for GEMM1 (layout verified r4/r5/r8) ----------------
__global__ void pack_weights2_kernel(const float* __restrict__ W1,
                                     const float* __restrict__ Wx,
                                     const float* __restrict__ sW1,
                                     const float* __restrict__ sWx,
                                     unsigned short* __restrict__ Wpack2){
  int j = blockIdx.x, r = blockIdx.y, c = threadIdx.x;
  const float* src;
  if (r < 80)      { int k = r/5, h = r%5;             src = W1  + (((k*D_ + j)*H_ + h)*IN_); }
  else if (r < 96) { int k = r-80;                     src = Wx  + ((k*D_ + j)*IN_); }
  else if (r < 176){ int rr = r-96; int k=rr/5,h=rr%5; src = sW1 + (((k*D_ + j)*H_ + h)*IN_); }
  else             { int k = r-176;                    src = sWx + ((k*D_ + j)*IN_); }
  int kk = c >> 5, ks = (c >> 3) & 3, e = c & 7;
  Wpack2[((((size_t)j*8 + kk)*192 + r)*4 + ks)*8 + e] = f2bf(src[c]);
}

// ---------------- b1pack[j][col 0..191] (f32; 0 on xdot cols) ----------------
__global__ void pack_b1_kernel(const float* __restrict__ b1, const float* __restrict__ sb1,
                               float* __restrict__ b1pack){
  int j = blockIdx.x, r = threadIdx.x;  // 192
  float v = 0.f;
  if (r < 80) v = b1[j*80 + r];
  else if (r >= 96 && r < 176) v = sb1[j*80 + (r-96)];
  b1pack[j*192 + r] = v;
}

// ---------------- B2packF: MFMA2 A-operand fragments (layout verified r5/r8) ----------------
__global__ void pack_b2f_kernel(const float* __restrict__ Wh, const float* __restrict__ sWh,
                                unsigned short* __restrict__ B2packF){
  int j = blockIdx.x, kk = blockIdx.y, t = threadIdx.x;  // 256 thr, 1024 elems
  #pragma unroll
  for (int q = 0; q < 4; ++q){
    int f = t*4 + q;                 // r*32 + lg*8 + e
    int e = f & 7, lg = (f >> 3) & 3, r = f >> 5;
    int c = kk*32 + lg*8 + e;        // 0..95
    int k = r & 15;
    int h = c - 5*k;
    float v = 0.f;
    if (h >= 0 && h < 5) v = (r < 16 ? Wh : sWh)[((size_t)k*D_ + j)*H_ + h];
    B2packF[((size_t)j*3 + kk)*1024 + f] = f2bf(v);
  }
}

// ---------------- masked-softmax weights, packed as f16 MFMA A-fragment (verified r8) ----------------
__global__ void compute_w_kernel(const float* __restrict__ targets, _Float16* __restrict__ wf16){
  int j = blockIdx.x;
  int i = threadIdx.x;
  if (i >= K_) return;
  float base[K_];
  base[0] = (i == 0) ? 1.f : 0.f;
  for (int c = 1; c <= i; ++c)
    base[c] = targets[(j*K_ + i)*(K_-1) + (c-1)] + ((c == i) ? 1.f : 0.f);
  float mx = base[0];
  for (int c = 1; c <= i; ++c) mx = fmaxf(mx, base[c]);
  float e[K_]; float s = 0.f;
  for (int c = 0; c <= i; ++c){ e[c] = expf(base[c] - mx); s += e[c]; }
  float inv = 1.f / s;
  for (int c = 0; c < K_; ++c){
    float w = (c <= i) ? e[c]*inv : 0.f;
    wf16[j*256 + ((c >> 2)*16 + i)*4 + (c & 3)] = (_Float16)w;
  }
}

// ---------------- main fused kernel: barrier-free + batched double-buffered B loads ----------------
// 2048 blocks x 256 thr (4 waves). Wave wv owns rows b0+wv*16..+15, all 192 cols, 4 j's.
// Per-wave LDS slice (8960 B): G[16][208]bf16 | Gx[16][17]f32 | Gsx[16][17]f32
__global__ __launch_bounds__(256, 2)
void main_kernel(const float* __restrict__ x_values,
                 const float* __restrict__ x_inputs,
                 const unsigned short* __restrict__ Wpack2,
                 const _Float16* __restrict__ wf16,
                 const float* __restrict__ b1pack,
                 const unsigned short* __restrict__ B2packF,
                 const float* __restrict__ b2, const float* __restrict__ sb2,
                 float* __restrict__ partial){
  __shared__ __align__(16) char sm[35840];

  const int t    = threadIdx.x;
  const int lane = t & 63, wv = t >> 6;
  const int l15  = lane & 15, lg = lane >> 4;

  // XCD-aware swizzle (bijective, 2048 = 8*256)
  const int bx  = blockIdx.x;
  const int xcd = bx & 7, q8 = bx >> 3;
  const int bt  = q8 & 127, jg = xcd*2 + (q8 >> 7);
  const int b0  = bt * 64;

  char* Gw = sm + wv*8960;
  unsigned short* G = (unsigned short*)Gw;     // [16][208]
  float* Gx  = (float*)(Gw + 6656);            // [16][17]
  float* Gsx = (float*)(Gw + 7744);            // [16][17]

  const int myrow = b0 + wv*16 + l15;

  f32x4 acc3 = {0.f,0.f,0.f,0.f};

  // B-fragment base for (jj, s): s = kc*4+kkl
  const unsigned short* wpbase = Wpack2 + (size_t)(jg*4)*8*6144 + l15*32 + lg*8;
  #define BPTR(jjx, sx) (wpbase + (size_t)((jjx)*8 + (sx))*6144)

  f32x4  av[8];
  bf16x8 bfr[2][12];

  // ================= prologue: A(jj0,kc0) + B batch (jj0,s0) =================
  {
    const float* ap = x_inputs + ((size_t)myrow*D_ + jg*4)*IN_;
    #pragma unroll
    for (int kkl = 0; kkl < 4; ++kkl){
      av[kkl*2]   = *(const f32x4*)(ap + kkl*32 + lg*8);
      av[kkl*2+1] = *(const f32x4*)(ap + kkl*32 + lg*8 + 4);
    }
    #pragma unroll
    for (int n = 0; n < 12; ++n) bfr[0][n] = *(const bf16x8*)(BPTR(0,0) + n*512);
  }

  for (int jj = 0; jj < 4; ++jj){
    const int j = jg*4 + jj;
    const float* aprow = x_inputs + ((size_t)myrow*D_ + j)*IN_;

    const f16x4 wfrag = *(const f16x4*)(wf16 + j*256 + lane*4);

    f32x4 acc1[12];
    #pragma unroll
    for (int n = 0; n < 12; ++n) acc1[n] = (f32x4){0.f,0.f,0.f,0.f};

    // cvt A(kc0) from prefetched av
    bf16x8 afp0[4], afp1[4];
    #pragma unroll
    for (int kkl = 0; kkl < 4; ++kkl){
      u32x4 at;
      at[0] = cvtpk(av[kkl*2][0],   av[kkl*2][1]);
      at[1] = cvtpk(av[kkl*2][2],   av[kkl*2][3]);
      at[2] = cvtpk(av[kkl*2+1][0], av[kkl*2+1][1]);
      at[3] = cvtpk(av[kkl*2+1][2], av[kkl*2+1][3]);
      afp0[kkl] = __builtin_bit_cast(bf16x8, at);
    }
    // issue A(kc1) loads
    #pragma unroll
    for (int kkl = 0; kkl < 4; ++kkl){
      av[kkl*2]   = *(const f32x4*)(aprow + 128 + kkl*32 + lg*8);
      av[kkl*2+1] = *(const f32x4*)(aprow + 128 + kkl*32 + lg*8 + 4);
    }

    // ---- s = 0..3 (kc0): prefetch batch s+1, MFMA batch s ----
    #pragma unroll
    for (int s = 0; s < 4; ++s){
      #pragma unroll
      for (int n = 0; n < 12; ++n)
        bfr[(s+1)&1][n] = *(const bf16x8*)(BPTR(jj, s+1) + n*512);
      #pragma unroll
      for (int n = 0; n < 12; ++n)
        acc1[n] = __builtin_amdgcn_mfma_f32_16x16x32_bf16(afp0[s], bfr[s&1][n], acc1[n], 0, 0, 0);
    }

    // cvt A(kc1); issue A(jj+1, kc0)
    #pragma unroll
    for (int kkl = 0; kkl < 4; ++kkl){
      u32x4 at;
      at[0] = cvtpk(av[kkl*2][0],   av[kkl*2][1]);
      at[1] = cvtpk(av[kkl*2][2],   av[kkl*2][3]);
      at[2] = cvtpk(av[kkl*2+1][0], av[kkl*2+1][1]);
      at[3] = cvtpk(av[kkl*2+1][2], av[kkl*2+1][3]);
      afp1[kkl] = __builtin_bit_cast(bf16x8, at);
    }
    if (jj < 3){
      #pragma unroll
      for (int kkl = 0; kkl < 4; ++kkl){
        av[kkl*2]   = *(const f32x4*)(aprow + IN_ + kkl*32 + lg*8);
        av[kkl*2+1] = *(const f32x4*)(aprow + IN_ + kkl*32 + lg*8 + 4);
      }
    }

    // ---- s = 4..7 (kc1): prefetch next batch (crosses jj boundary), MFMA batch s ----
    #pragma unroll
    for (int s = 4; s < 8; ++s){
      if (!(jj == 3 && s == 7)){
        const int njj = (s == 7) ? jj+1 : jj;
        const int ns  = (s == 7) ? 0 : s+1;
        #pragma unroll
        for (int n = 0; n < 12; ++n)
          bfr[(s+1)&1][n] = *(const bf16x8*)(BPTR(njj, ns) + n*512);
      }
      #pragma unroll
      for (int n = 0; n < 12; ++n)
        acc1[n] = __builtin_amdgcn_mfma_f32_16x16x32_bf16(afp1[s-4], bfr[s&1][n], acc1[n], 0, 0, 0);
    }

    // ---- G write: lrelu+b1 on hidden cols; xdot cols -> Gx/Gsx, zeros into G ----
    #pragma unroll
    for (int n = 0; n < 12; ++n){
      if (n == 5){
        #pragma unroll
        for (int e = 0; e < 4; ++e){
          Gx[(lg*4+e)*17 + l15] = acc1[5][e];
          G[(lg*4+e)*208 + 80 + l15] = 0;
        }
      } else if (n == 11){
        #pragma unroll
        for (int e = 0; e < 4; ++e){
          Gsx[(lg*4+e)*17 + l15] = acc1[11][e];
          G[(lg*4+e)*208 + 176 + l15] = 0;
        }
      } else {
        const float b1v = b1pack[j*192 + n*16 + l15];
        #pragma unroll
        for (int e = 0; e < 4; ++e){
          float v = acc1[n][e] + b1v;
          v = fmaxf(v, 0.2f*v);
          G[(lg*4+e)*208 + n*16 + l15] = f2bf(v);
        }
      }
    }

    // ---- MFMA2: D[k][brow] = W2 * G^T + (xdot + bias); wave-private ----
    {
      f32x4 accm = *(const f32x4*)(Gx  + l15*17 + lg*4) + *(const f32x4*)(b2  + j*16 + lg*4);
      f32x4 accs = *(const f32x4*)(Gsx + l15*17 + lg*4) + *(const f32x4*)(sb2 + j*16 + lg*4);
      #pragma unroll
      for (int kk = 0; kk < 3; ++kk){
        bf16x8 a0 = *(const bf16x8*)(B2packF + ((size_t)j*3 + kk)*1024 + l15*32 + lg*8);
        bf16x8 a1 = *(const bf16x8*)(B2packF + ((size_t)j*3 + kk)*1024 + (16+l15)*32 + lg*8);
        bf16x8 g0 = *(const bf16x8*)((char*)G + l15*416       + kk*64 + lg*16);
        bf16x8 g1 = *(const bf16x8*)((char*)G + l15*416 + 192 + kk*64 + lg*16);
        accm = __builtin_amdgcn_mfma_f32_16x16x32_bf16(a0, g0, accm, 0, 0, 0);
        accs = __builtin_amdgcn_mfma_f32_16x16x32_bf16(a1, g1, accs, 0, 0, 0);
      }

      // ---- E1: nll nodes; lane holds k = lg*4+e for row brow = l15 ----
      const float xv = x_values[(size_t)myrow*D_ + j];
      float nn4[4];
      #pragma unroll
      for (int e = 0; e < 4; ++e){
        float mean = accm[e];
        float shv  = accs[e];
        float sg   = __fdividef(10.f, 1.f + __expf(-shv));
        float var  = fmaxf(sg*sg, 1e-6f);
        float d    = xv - mean;
        nn4[e] = 0.5f*(__logf(var) + __fdividef(d*d, var));
      }

      // ---- E2 as MFMA: acc3 += w(f16) x nll(f16) ----
      f16x2 p0 = __builtin_bit_cast(f16x2, __builtin_amdgcn_cvt_pkrtz(nn4[0], nn4[1]));
      f16x2 p1 = __builtin_bit_cast(f16x2, __builtin_amdgcn_cvt_pkrtz(nn4[2], nn4[3]));
      f16x4 nf = {p0[0], p0[1], p1[0], p1[1]};
      acc3 = __builtin_amdgcn_mfma_f32_16x16x16f16(wfrag, nf, acc3, 0, 0, 0);
    }
  }

  // final store: partial[jg][b][i]
  *(f32x4*)(partial + ((size_t)jg*B_TOT + myrow)*K_ + lg*4) = acc3;
}

// ---------------- final reduce over 16 j-groups ----------------
__global__ void reduce_kernel(const float* __restrict__ partial, float* __restrict__ out){
  int idx = blockIdx.x*256 + threadIdx.x;   // 131072
  float s = 0.f;
  #pragma unroll
  for (int g = 0; g < 16; ++g) s += partial[(size_t)g*(B_TOT*K_) + idx];
  out[idx] = s;
}

extern "C" void kernel_launch(void* const* d_in, const int* in_sizes, int n_in,
                              void* d_out, int out_size, void* d_ws, size_t ws_size,
                              hipStream_t stream){
  const float* x_values = (const float*)d_in[0];
  const float* x_inputs = (const float*)d_in[1];
  const float* targets  = (const float*)d_in[2];
  const float* W1  = (const float*)d_in[3];
  const float* b1  = (const float*)d_in[4];
  const float* Wh  = (const float*)d_in[5];
  const float* Wx  = (const float*)d_in[6];
  const float* b2  = (const float*)d_in[7];
  const float* sW1 = (const float*)d_in[8];
  const float* sb1 = (const float*)d_in[9];
  const float* sWh = (const float*)d_in[10];
  const float* sWx = (const float*)d_in[11];
  const float* sb2 = (const float*)d_in[12];
  (void)in_sizes; (void)n_in; (void)out_size; (void)ws_size;

  char* ws = (char*)d_ws;
  unsigned short* Wpack2  = (unsigned short*)ws;             // 6,291,456
  float* b1pack           = (float*)(ws + 6291456);          // 49,152
  unsigned short* B2packF = (unsigned short*)(ws + 6340608); // 393,216
  _Float16* wf16          = (_Float16*)(ws + 6733824);       // 32,768
  float* partial          = (float*)(ws + 6766592);          // 8,388,608
  float* out = (float*)d_out;

  pack_weights2_kernel<<<dim3(64, 192), 256, 0, stream>>>(W1, Wx, sW1, sWx, Wpack2);
  pack_b1_kernel<<<dim3(64), 192, 0, stream>>>(b1, sb1, b1pack);
  pack_b2f_kernel<<<dim3(64, 3), 256, 0, stream>>>(Wh, sWh, B2packF);
  compute_w_kernel<<<dim3(64), 64, 0, stream>>>(targets, wf16);
  main_kernel<<<dim3(2048), 256, 0, stream>>>(x_values, x_inputs, Wpack2, wf16,
                                              b1pack, B2packF, b2, sb2, partial);
  reduce_kernel<<<dim3(512), 256, 0, stream>>>(partial, out);
}

// Round 10
// 214.031 us; speedup vs baseline: 1.6377x; 1.3571x over previous
//
#include <hip/hip_runtime.h>

typedef float f32x4 __attribute__((ext_vector_type(4)));
typedef short bf16x8 __attribute__((ext_vector_type(8)));
typedef unsigned int u32x4 __attribute__((ext_vector_type(4)));
typedef _Float16 f16x2 __attribute__((ext_vector_type(2)));
typedef _Float16 f16x4 __attribute__((ext_vector_type(4)));

#define B_TOT 8192
#define D_ 64
#define K_ 16
#define H_ 5
#define IN_ 256

__device__ __forceinline__ unsigned short f2bf(float f){
  unsigned int u = __float_as_uint(f);
  u += 0x7fffu + ((u >> 16) & 1u);   // round-to-nearest-even
  return (unsigned short)(u >> 16);
}

__device__ __forceinline__ unsigned int cvtpk(float lo, float hi){
  unsigned int r;
  asm("v_cvt_pk_bf16_f32 %0, %1, %2" : "=v"(r) : "v"(lo), "v"(hi));
  return r;
}

// ---------------- Wpack2: pre-fragmented B for GEMM1 (layout verified r4-r9) ----------------
__global__ void pack_weights2_kernel(const float* __restrict__ W1,
                                     const float* __restrict__ Wx,
                                     const float* __restrict__ sW1,
                                     const float* __restrict__ sWx,
                                     unsigned short* __restrict__ Wpack2){
  int j = blockIdx.x, r = blockIdx.y, c = threadIdx.x;
  const float* src;
  if (r < 80)      { int k = r/5, h = r%5;             src = W1  + (((k*D_ + j)*H_ + h)*IN_); }
  else if (r < 96) { int k = r-80;                     src = Wx  + ((k*D_ + j)*IN_); }
  else if (r < 176){ int rr = r-96; int k=rr/5,h=rr%5; src = sW1 + (((k*D_ + j)*H_ + h)*IN_); }
  else             { int k = r-176;                    src = sWx + ((k*D_ + j)*IN_); }
  int kk = c >> 5, ks = (c >> 3) & 3, e = c & 7;
  Wpack2[((((size_t)j*8 + kk)*192 + r)*4 + ks)*8 + e] = f2bf(src[c]);
}

// ---------------- b1pack[j][col 0..191] (f32; 0 on xdot cols) ----------------
__global__ void pack_b1_kernel(const float* __restrict__ b1, const float* __restrict__ sb1,
                               float* __restrict__ b1pack){
  int j = blockIdx.x, r = threadIdx.x;  // 192
  float v = 0.f;
  if (r < 80) v = b1[j*80 + r];
  else if (r >= 96 && r < 176) v = sb1[j*80 + (r-96)];
  b1pack[j*192 + r] = v;
}

// ---------------- B2packF: MFMA2 A-operand fragments (layout verified r5/r8/r9) ----------------
__global__ void pack_b2f_kernel(const float* __restrict__ Wh, const float* __restrict__ sWh,
                                unsigned short* __restrict__ B2packF){
  int j = blockIdx.x, kk = blockIdx.y, t = threadIdx.x;  // 256 thr, 1024 elems
  #pragma unroll
  for (int q = 0; q < 4; ++q){
    int f = t*4 + q;                 // r*32 + lg*8 + e
    int e = f & 7, lg = (f >> 3) & 3, r = f >> 5;
    int c = kk*32 + lg*8 + e;        // 0..95
    int k = r & 15;
    int h = c - 5*k;
    float v = 0.f;
    if (h >= 0 && h < 5) v = (r < 16 ? Wh : sWh)[((size_t)k*D_ + j)*H_ + h];
    B2packF[((size_t)j*3 + kk)*1024 + f] = f2bf(v);
  }
}

// ---------------- masked-softmax weights as f16 MFMA A-fragment (verified r8/r9) ----------------
__global__ void compute_w_kernel(const float* __restrict__ targets, _Float16* __restrict__ wf16){
  int j = blockIdx.x;
  int i = threadIdx.x;
  if (i >= K_) return;
  float base[K_];
  base[0] = (i == 0) ? 1.f : 0.f;
  for (int c = 1; c <= i; ++c)
    base[c] = targets[(j*K_ + i)*(K_-1) + (c-1)] + ((c == i) ? 1.f : 0.f);
  float mx = base[0];
  for (int c = 1; c <= i; ++c) mx = fmaxf(mx, base[c]);
  float e[K_]; float s = 0.f;
  for (int c = 0; c <= i; ++c){ e[c] = expf(base[c] - mx); s += e[c]; }
  float inv = 1.f / s;
  for (int c = 0; c < K_; ++c){
    float w = (c <= i) ? e[c]*inv : 0.f;
    wf16[j*256 + ((c >> 2)*16 + i)*4 + (c & 3)] = (_Float16)w;
  }
}

// ---------------- main fused kernel: lockstep block (min B-traffic) + issue-early pipeline ----------------
// grid (16 jg, 128 bt), 256 thr (4 waves). Block: 64 rows x 192 cols x 4 j. Waves split cols (48 each).
// LDS 52224: A[64][128]bf16 swz 16384 | G[64][200]bf16 25600 | Gx[64][20]f32 5120 | Gsx[64][20]f32 5120
__global__ __launch_bounds__(256, 2)
void main_kernel(const float* __restrict__ x_values,
                 const float* __restrict__ x_inputs,
                 const unsigned short* __restrict__ Wpack2,
                 const _Float16* __restrict__ wf16,
                 const float* __restrict__ b1pack,
                 const unsigned short* __restrict__ B2packF,
                 const float* __restrict__ b2, const float* __restrict__ sb2,
                 float* __restrict__ partial){
  __shared__ __align__(16) char sm[52224];
  unsigned short* G = (unsigned short*)(sm + 16384); // [64][200]
  float* Gx  = (float*)(sm + 41984);                 // [64][20]
  float* Gsx = (float*)(sm + 47104);                 // [64][20]

  const int t    = threadIdx.x;
  const int lane = t & 63, wv = t >> 6;
  const int l15  = lane & 15, lg = lane >> 4;
  const int r0   = t >> 4, cb = t & 15;              // staging role
  const int jg = blockIdx.x, b0 = blockIdx.y * 64;

  f32x4  av[8];
  bf16x8 bfr[12];
  f32x4  acc3 = {0.f,0.f,0.f,0.f};

  // ---- helpers as lambdas (all compile-time unrolled) ----
  auto issueA = [&](int j, int kc){
    const float* ap = x_inputs + ((size_t)(b0 + r0)*D_ + j)*IN_ + kc*128 + cb*8;
    #pragma unroll
    for (int p = 0; p < 4; ++p){
      av[p*2]   = *(const f32x4*)(ap + (size_t)p*16*D_*IN_);
      av[p*2+1] = *(const f32x4*)(ap + (size_t)p*16*D_*IN_ + 4);
    }
  };
  auto cvtWriteA = [&](){
    #pragma unroll
    for (int p = 0; p < 4; ++p){
      const int row = p*16 + r0;
      u32x4 o;
      o[0] = cvtpk(av[p*2][0],   av[p*2][1]);
      o[1] = cvtpk(av[p*2][2],   av[p*2][3]);
      o[2] = cvtpk(av[p*2+1][0], av[p*2+1][1]);
      o[3] = cvtpk(av[p*2+1][2], av[p*2+1][3]);
      *(u32x4*)(sm + row*256 + ((cb*16) ^ ((row & 7) << 4))) = o;
    }
  };
  auto issueB = [&](int j, int kc){
    #pragma unroll
    for (int kkl = 0; kkl < 4; ++kkl)
      #pragma unroll
      for (int n = 0; n < 3; ++n){
        const int o = wv*48 + n*16 + l15;
        bfr[kkl*3+n] = *(const bf16x8*)(Wpack2 + ((((size_t)j*8 + kc*4 + kkl)*192 + o)*4 + lg)*8);
      }
  };

  // ================= prologue =================
  issueA(jg*4, 0);

  for (int jj = 0; jj < 4; ++jj){
    const int j = jg*4 + jj;

    f32x4 acc1[4][3];
    #pragma unroll
    for (int m = 0; m < 4; ++m)
      #pragma unroll
      for (int n = 0; n < 3; ++n) acc1[m][n] = (f32x4){0.f,0.f,0.f,0.f};

    // ---- P0: issue B(kc0); cvt+write A(kc0) ----
    issueB(j, 0);
    __builtin_amdgcn_sched_barrier(0);
    cvtWriteA();
    __syncthreads();                                  // bar A

    // ---- P1: issue A(kc1); MFMA kc0 ----
    issueA(j, 1);
    __builtin_amdgcn_sched_barrier(0);
    #pragma unroll
    for (int kkl = 0; kkl < 4; ++kkl){
      bf16x8 af[4];
      #pragma unroll
      for (int m = 0; m < 4; ++m){
        const int row = m*16 + l15;
        af[m] = *(const bf16x8*)(sm + row*256 + ((kkl*64 + lg*16) ^ ((row & 7) << 4)));
      }
      #pragma unroll
      for (int m = 0; m < 4; ++m)
        #pragma unroll
        for (int n = 0; n < 3; ++n)
          acc1[m][n] = __builtin_amdgcn_mfma_f32_16x16x32_bf16(af[m], bfr[kkl*3+n], acc1[m][n], 0, 0, 0);
    }
    __syncthreads();                                  // bar B

    // ---- P2: issue B(kc1); cvt+write A(kc1) ----
    issueB(j, 1);
    __builtin_amdgcn_sched_barrier(0);
    cvtWriteA();
    __syncthreads();                                  // bar C

    // ---- P3: issue A(j+1,kc0) + epilogue operands; MFMA kc1; G write ----
    bf16x8 b2tf[6];
    f16x4  wfrag;
    float  b1f[12];
    if (jj < 3) issueA(j+1, 0);
    #pragma unroll
    for (int kk = 0; kk < 3; ++kk){
      b2tf[kk]   = *(const bf16x8*)(B2packF + ((size_t)j*3 + kk)*1024 + l15*32 + lg*8);
      b2tf[3+kk] = *(const bf16x8*)(B2packF + ((size_t)j*3 + kk)*1024 + (16+l15)*32 + lg*8);
    }
    wfrag = *(const f16x4*)(wf16 + j*256 + lane*4);
    #pragma unroll
    for (int n = 0; n < 12; ++n) b1f[n] = b1pack[j*192 + n*16 + l15];
    __builtin_amdgcn_sched_barrier(0);
    #pragma unroll
    for (int kkl = 0; kkl < 4; ++kkl){
      bf16x8 af[4];
      #pragma unroll
      for (int m = 0; m < 4; ++m){
        const int row = m*16 + l15;
        af[m] = *(const bf16x8*)(sm + row*256 + ((kkl*64 + lg*16) ^ ((row & 7) << 4)));
      }
      #pragma unroll
      for (int m = 0; m < 4; ++m)
        #pragma unroll
        for (int n = 0; n < 3; ++n)
          acc1[m][n] = __builtin_amdgcn_mfma_f32_16x16x32_bf16(af[m], bfr[kkl*3+n], acc1[m][n], 0, 0, 0);
    }
    // G write (lrelu+b1 fused; xdot cols -> f32 side buffers, bf16 zeros into G)
    #pragma unroll
    for (int n = 0; n < 3; ++n){
      const int col = wv*48 + n*16 + l15;
      const int nid = wv*3 + n;                       // 0..11 column-slab id
      const bool isx  = (col >= 80 && col < 96);
      const bool issx = (col >= 176);
      #pragma unroll
      for (int m = 0; m < 4; ++m){
        const int row = m*16 + lg*4;
        if (isx){
          #pragma unroll
          for (int e = 0; e < 4; ++e){
            Gx[(row+e)*20 + (col-80)] = acc1[m][n][e];
            G[(row+e)*200 + col] = 0;
          }
        } else if (issx){
          #pragma unroll
          for (int e = 0; e < 4; ++e){
            Gsx[(row+e)*20 + (col-176)] = acc1[m][n][e];
            G[(row+e)*200 + col] = 0;
          }
        } else {
          #pragma unroll
          for (int e = 0; e < 4; ++e){
            float v = acc1[m][n][e] + b1f[nid];
            v = fmaxf(v, 0.2f*v);
            G[(row+e)*200 + col] = f2bf(v);
          }
        }
      }
    }
    __syncthreads();                                  // bar D

    // ---- P4: MFMA2 + E1 + E2 (wave handles rows brow = wv*16+l15) ----
    {
      const int brow = wv*16 + l15;
      f32x4 accm = *(const f32x4*)(Gx  + brow*20 + lg*4) + *(const f32x4*)(b2  + j*16 + lg*4);
      f32x4 accs = *(const f32x4*)(Gsx + brow*20 + lg*4) + *(const f32x4*)(sb2 + j*16 + lg*4);
      #pragma unroll
      for (int kk = 0; kk < 3; ++kk){
        bf16x8 g0 = *(const bf16x8*)((char*)G + brow*400       + kk*64 + lg*16);
        bf16x8 g1 = *(const bf16x8*)((char*)G + brow*400 + 192 + kk*64 + lg*16);
        accm = __builtin_amdgcn_mfma_f32_16x16x32_bf16(b2tf[kk],   g0, accm, 0, 0, 0);
        accs = __builtin_amdgcn_mfma_f32_16x16x32_bf16(b2tf[3+kk], g1, accs, 0, 0, 0);
      }

      const float xv = x_values[(size_t)(b0 + brow)*D_ + j];
      float nn4[4];
      #pragma unroll
      for (int e = 0; e < 4; ++e){
        float mean = accm[e];
        float shv  = accs[e];
        float sg   = __fdividef(10.f, 1.f + __expf(-shv));
        float var  = fmaxf(sg*sg, 1e-6f);
        float d    = xv - mean;
        nn4[e] = 0.5f*(__logf(var) + __fdividef(d*d, var));
      }

      f16x2 p0 = __builtin_bit_cast(f16x2, __builtin_amdgcn_cvt_pkrtz(nn4[0], nn4[1]));
      f16x2 p1 = __builtin_bit_cast(f16x2, __builtin_amdgcn_cvt_pkrtz(nn4[2], nn4[3]));
      f16x4 nf = {p0[0], p0[1], p1[0], p1[1]};
      acc3 = __builtin_amdgcn_mfma_f32_16x16x16f16(wfrag, nf, acc3, 0, 0, 0);
    }
    // next j's P0 writes A-buf (safe: last A-read was before bar D) and G (safe: barriers A'-C' precede)
  }

  // final store: partial[jg][b][i], lane covers i = lg*4..+3 for b = b0+wv*16+l15
  *(f32x4*)(partial + ((size_t)jg*B_TOT + b0 + wv*16 + l15)*K_ + lg*4) = acc3;
}

// ---------------- final reduce over 16 j-groups ----------------
__global__ void reduce_kernel(const float* __restrict__ partial, float* __restrict__ out){
  int idx = blockIdx.x*256 + threadIdx.x;   // 131072
  float s = 0.f;
  #pragma unroll
  for (int g = 0; g < 16; ++g) s += partial[(size_t)g*(B_TOT*K_) + idx];
  out[idx] = s;
}

extern "C" void kernel_launch(void* const* d_in, const int* in_sizes, int n_in,
                              void* d_out, int out_size, void* d_ws, size_t ws_size,
                              hipStream_t stream){
  const float* x_values = (const float*)d_in[0];
  const float* x_inputs = (const float*)d_in[1];
  const float* targets  = (const float*)d_in[2];
  const float* W1  = (const float*)d_in[3];
  const float* b1  = (const float*)d_in[4];
  const float* Wh  = (const float*)d_in[5];
  const float* Wx  = (const float*)d_in[6];
  const float* b2  = (const float*)d_in[7];
  const float* sW1 = (const float*)d_in[8];
  const float* sb1 = (const float*)d_in[9];
  const float* sWh = (const float*)d_in[10];
  const float* sWx = (const float*)d_in[11];
  const float* sb2 = (const float*)d_in[12];
  (void)in_sizes; (void)n_in; (void)out_size; (void)ws_size;

  char* ws = (char*)d_ws;
  unsigned short* Wpack2  = (unsigned short*)ws;             // 6,291,456
  float* b1pack           = (float*)(ws + 6291456);          // 49,152
  unsigned short* B2packF = (unsigned short*)(ws + 6340608); // 393,216
  _Float16* wf16          = (_Float16*)(ws + 6733824);       // 32,768
  float* partial          = (float*)(ws + 6766592);          // 8,388,608
  float* out = (float*)d_out;

  pack_weights2_kernel<<<dim3(64, 192), 256, 0, stream>>>(W1, Wx, sW1, sWx, Wpack2);
  pack_b1_kernel<<<dim3(64), 192, 0, stream>>>(b1, sb1, b1pack);
  pack_b2f_kernel<<<dim3(64, 3), 256, 0, stream>>>(Wh, sWh, B2packF);
  compute_w_kernel<<<dim3(64), 64, 0, stream>>>(targets, wf16);
  main_kernel<<<dim3(16, 128), 256, 0, stream>>>(x_values, x_inputs, Wpack2, wf16,
                                                 b1pack, B2packF, b2, sb2, partial);
  reduce_kernel<<<dim3(512), 256, 0, stream>>>(partial, out);
}